// Round 1
// baseline (106.493 us; speedup 1.0000x reference)
//
#include <hip/hip_runtime.h>
#include <cstdint>
#include <cstddef>

// ---------------------------------------------------------------------------
// ChannelWiseCrossAttention: B=4, C=64, H=W=64, N=4096
// Workspace layouts are MFMA-fragment-major (wave-contiguous loads):
//   Q,K per (b, 32-row tile): [kc(4)][hi(2)][il(32)][e(8)]  (2048 elems)
//     element (row il, c = kc*16+hi*8+e)
//   V  per (b, 32-col tile):  [kcs(4)][hi(2)][c(64)][e(4)]  (2048 elems)
//     element (c, j = kcs*8+hi*4+e)
// qkv: ONE 768-block kernel; kind = bid>>8 in {Q,K,V}; block = 64 pixels of
//   one projection. 3x the waves/CU of the fused version (latency-bound fix).
// attn: 256 blocks x 8 waves; block = 64 Q-rows (2 subtiles); wave = 1/8 of j.
//   S^T = K Q^T (mfma_f32_32x32x16_bf16), p = exp2(S') UNSHIFTED (constant
//   shift cancels in O/l), O^T += V P^T (32x32x8; S^T C/D regs are B-frags).
//   8-wave partial (O,l) combine: 3-slot LDS tree + per-wave lsum array.
// Round 10 changes (VALU-bound theory):
//   - st zero-init via persistent zf block fed as MFMA C operand (-32 v_mov/t)
//   - lsum computed by ones-A pv_mfma against bp frags (-38 VALU adds/t,
//     kills the final shfl_xor too; moves work to slack MFMA pipe)
//   - s_setprio(1) around MFMA clusters (m191 regime: independent waves)
// ---------------------------------------------------------------------------

typedef __bf16 bf16x4 __attribute__((ext_vector_type(4)));
typedef __bf16 bf16x8 __attribute__((ext_vector_type(8)));
typedef float  f32x4  __attribute__((ext_vector_type(4)));
typedef float  f32x16 __attribute__((ext_vector_type(16)));
typedef short  s16x4  __attribute__((ext_vector_type(4)));

constexpr int C = 64;
constexpr int N = 4096;
constexpr float LOG2E = 1.44269504088896340736f;

static __device__ __forceinline__ f32x4 mfma16(bf16x8 a, bf16x8 b, f32x4 c) {
    return __builtin_amdgcn_mfma_f32_16x16x32_bf16(a, b, c, 0, 0, 0);
}
static __device__ __forceinline__ f32x16 mfma32(bf16x8 a, bf16x8 b, f32x16 c) {
    return __builtin_amdgcn_mfma_f32_32x32x16_bf16(a, b, c, 0, 0, 0);
}
// 32x32x8 bf16 (A/B = 4 bf16, k = 4*hi + j). Native if available, else
// zero-padded 32x32x16 (logical k at slot j in both operands).
static __device__ __forceinline__ f32x16 pv_mfma(bf16x4 a, bf16x4 b, f32x16 c) {
#if __has_builtin(__builtin_amdgcn_mfma_f32_32x32x8bf16_1k)
    union U { bf16x4 h; s16x4 s; };
    U ua; ua.h = a;
    U ub; ub.h = b;
    return __builtin_amdgcn_mfma_f32_32x32x8bf16_1k(ua.s, ub.s, c, 0, 0, 0);
#else
    const __bf16 z = (__bf16)0.0f;
    bf16x8 a8 = {a[0], a[1], a[2], a[3], z, z, z, z};
    bf16x8 b8 = {b[0], b[1], b[2], b[3], z, z, z, z};
    return __builtin_amdgcn_mfma_f32_32x32x16_bf16(a8, b8, c, 0, 0, 0);
#endif
}
static __device__ __forceinline__ float fast_exp2(float x) {
#if __has_builtin(__builtin_amdgcn_exp2f)
    return __builtin_amdgcn_exp2f(x);
#else
    return exp2f(x);
#endif
}

// ---------------------------------------------------------------------------
// QKV conv, 3-way split. grid = 768 x 256 thr. kind = bid>>8: 0=Q, 1=K, 2=V.
// Each block: one projection, 64 pixels, 4 waves x 16 pixels.
//   Q,K: D[n][o] = X^T W^T (A = x frag, B = W row-major from LDS)
//   V  : D[o][n] = W X     (A = W row-major from LDS, B = x frag)
// Results round-trip a padded LDS transpose so all global stores are 16B.
// ---------------------------------------------------------------------------
__global__ __launch_bounds__(256) void qkv_kernel(
    const float* __restrict__ x1, const float* __restrict__ x2,
    const float* __restrict__ wq, const float* __restrict__ bq,
    const float* __restrict__ wk, const float* __restrict__ bk,
    const float* __restrict__ wv, const float* __restrict__ bv,
    __bf16* __restrict__ qo, __bf16* __restrict__ ko, __bf16* __restrict__ vo)
{
    __shared__ __bf16 wl[64][72];     // W row-major, 9 KB
    __shared__ __bf16 tout[64][72];   // [pixel][o] transpose buffer, 9 KB

    const int bid  = blockIdx.x;
    const int kind = bid >> 8;                 // 0=Q, 1=K, 2=V (block-uniform)
    const int pg   = bid & 255;
    const int b     = pg >> 6;
    const int nbase = (pg & 63) * 64;
    const int tid   = threadIdx.x;

    const float* wsel = kind == 0 ? wq : (kind == 1 ? wk : wv);
    const float* bsel = kind == 0 ? bq : (kind == 1 ? bk : bv);
    const float* xsel = kind == 0 ? x1 : x2;
    __bf16*      osel = kind == 0 ? qo : (kind == 1 ? ko : vo);

    // ---- stage W (64x64 fp32 -> bf16 LDS) ----
#pragma unroll
    for (int i = 0; i < 4; ++i) {
        int idx = i * 256 + tid;
        int row = idx >> 4, c4 = (idx & 15) * 4;
        float4 a = *(const float4*)(wsel + row * 64 + c4);
        bf16x4 h = {(__bf16)a.x, (__bf16)a.y, (__bf16)a.z, (__bf16)a.w};
        *(bf16x4*)&wl[row][c4] = h;
    }
    __syncthreads();

    const int wave = tid >> 6, lane = tid & 63;
    const int l = lane & 15, qd = lane >> 4;
    const int p = nbase + wave * 16 + l;       // this lane's pixel

    // x fragment: A/B[k=c][pixel p], c = ks*32 + qd*8 + j
    const float* xb = xsel + (size_t)b * C * N + p;
    bf16x8 ax[2];
#pragma unroll
    for (int ks = 0; ks < 2; ++ks)
#pragma unroll
        for (int j = 0; j < 8; ++j)
            ax[ks][j] = (__bf16)xb[(size_t)(ks * 32 + qd * 8 + j) * N];

    if (kind < 2) {
        // ---- Q/K: D[pixel][o] ----
        const float scale = kind == 0 ? LOG2E : 1.0f;
#pragma unroll
        for (int ot = 0; ot < 4; ++ot) {
            const float bb = bsel[ot * 16 + l];
            f32x4 acc = {bb, bb, bb, bb};
#pragma unroll
            for (int ks = 0; ks < 2; ++ks) {
                bf16x8 bw = *(const bf16x8*)&wl[ot * 16 + l][ks * 32 + qd * 8];
                acc = mfma16(ax[ks], bw, acc);
            }
#pragma unroll
            for (int r = 0; r < 4; ++r) {
                int px = wave * 16 + qd * 4 + r;
                tout[px][ot * 16 + l] = (__bf16)(acc[r] * scale);
            }
        }
        __syncthreads();

        // ---- drain: frag-major 16B contiguous stores ----
        const int tile = tid >> 7, t7 = tid & 127;
        const int kc = t7 >> 5, h2 = (t7 >> 4) & 1, ilp = (t7 & 15) * 2;
        const size_t tb = ((size_t)b * 128 + (nbase >> 5) + tile) * 2048;
        const size_t off = tb + kc * 512 + h2 * 256 + ilp * 8;
        bf16x8 ra = *(const bf16x8*)&tout[tile * 32 + ilp][kc * 16 + h2 * 8];
        bf16x8 rb = *(const bf16x8*)&tout[tile * 32 + ilp + 1][kc * 16 + h2 * 8];
        *(bf16x8*)&osel[off]     = ra;
        *(bf16x8*)&osel[off + 8] = rb;
    } else {
        // ---- V: D[o][pixel] -> tout[pixel][o] ----
#pragma unroll
        for (int ct = 0; ct < 4; ++ct) {
            f32x4 acc;
#pragma unroll
            for (int r = 0; r < 4; ++r) acc[r] = bsel[ct * 16 + qd * 4 + r];
#pragma unroll
            for (int ks = 0; ks < 2; ++ks) {
                bf16x8 aw = *(const bf16x8*)&wl[ct * 16 + l][ks * 32 + qd * 8];
                acc = mfma16(aw, ax[ks], acc);
            }
            bf16x4 pk = {(__bf16)acc[0], (__bf16)acc[1], (__bf16)acc[2], (__bf16)acc[3]};
            *(bf16x4*)&tout[wave * 16 + l][ct * 16 + qd * 4] = pk;
        }
        __syncthreads();

        // ---- drain: [kcs][vhi][c][e4], 16B contiguous stores ----
        const int tile = tid >> 7, t7 = tid & 127;
        const int g = t7 >> 5, vh = (t7 >> 4) & 1, c0 = (t7 & 15) * 4;
        const int pxb = tile * 32 + g * 8 + vh * 4;
        bf16x4 e0 = *(const bf16x4*)&tout[pxb + 0][c0];
        bf16x4 e1 = *(const bf16x4*)&tout[pxb + 1][c0];
        bf16x4 e2 = *(const bf16x4*)&tout[pxb + 2][c0];
        bf16x4 e3 = *(const bf16x4*)&tout[pxb + 3][c0];
        bf16x8 o1, o2;
        o1[0]=e0[0]; o1[1]=e1[0]; o1[2]=e2[0]; o1[3]=e3[0];
        o1[4]=e0[1]; o1[5]=e1[1]; o1[6]=e2[1]; o1[7]=e3[1];
        o2[0]=e0[2]; o2[1]=e1[2]; o2[2]=e2[2]; o2[3]=e3[2];
        o2[4]=e0[3]; o2[5]=e1[3]; o2[6]=e2[3]; o2[7]=e3[3];
        const size_t tb = ((size_t)b * 128 + (nbase >> 5) + tile) * 2048;
        const size_t off = tb + g * 512 + vh * 256 + c0 * 4;
        *(bf16x8*)&osel[off]     = o1;
        *(bf16x8*)&osel[off + 8] = o2;
    }
}

// ---------------------------------------------------------------------------
// Attention. grid = 256 blocks x 512 thr.
// Block = (b, 64-row Q-tile = 2 subtiles); wave w owns j-tiles [w*16,w*16+16).
// 32x32x16: A/B 8 elems k=(lane>>5)*8+j; C/D row=(r&3)+8*(r>>2)+4*hi, col=il.
// ---------------------------------------------------------------------------
__global__ __launch_bounds__(512, 2) void attn_kernel(
    const __bf16* __restrict__ qg, const __bf16* __restrict__ kg,
    const __bf16* __restrict__ vg, const float* __restrict__ x1,
    const float* __restrict__ gamma, float* __restrict__ out)
{
    __shared__ float lds_acc[3][64][64];   // 3 combine slots, 48 KB, [c][i]
    __shared__ float lds_l[8][64];         // per-wave lsum partials, [w][i]

    const int bid = blockIdx.x;
    const int xcd = bid & 7;
    const int b   = xcd >> 1;
    const int rt  = ((bid >> 3) << 1) | (xcd & 1);   // 0..63 (64-row tile)
    const int ibase = rt * 64;

    const int tid  = threadIdx.x;
    const int wave = tid >> 6, lane = tid & 63;
    const int il = lane & 31, hi = lane >> 5;

    const __bf16* qt = qg + ((size_t)b * 128 + rt * 2) * 2048;
    const __bf16* kt = kg + (size_t)b * 128 * 2048 + (size_t)(wave * 16) * 2048;
    const __bf16* vt = vg + (size_t)b * 128 * 2048 + (size_t)(wave * 16) * 2048;

    // Q B-frags for both 32-row subtiles: 1 KB contiguous per load
    bf16x8 bqf[2][4];
#pragma unroll
    for (int qs = 0; qs < 2; ++qs)
#pragma unroll
        for (int kc = 0; kc < 4; ++kc)
            bqf[qs][kc] = *(const bf16x8*)(qt + qs * 2048 + kc * 512 + lane * 8);

    // persistent zero block: C operand for first MFMA of each accumulation
    // chain (replaces 32 v_mov zero-inits per t-iter per wave)
    f32x16 zf;
#pragma unroll
    for (int r = 0; r < 16; ++r) zf[r] = 0.f;

    // all-ones A-frag: row-sum-by-MFMA for the softmax denominator
    bf16x4 ones4;
#pragma unroll
    for (int e = 0; e < 4; ++e) ones4[e] = (__bf16)1.0f;

    f32x16 accO[4];   // [qs*2 + ct]
#pragma unroll
    for (int a = 0; a < 4; ++a)
#pragma unroll
        for (int r = 0; r < 16; ++r) accO[a][r] = 0.f;
    float lsum[2] = {0.f, 0.f};

    bf16x8 akf[2][4];   // K frags, double-buffered
    bf16x4 avf[2][4];   // V frags [ct][kcs]

#pragma unroll
    for (int kc = 0; kc < 4; ++kc)
        akf[0][kc] = *(const bf16x8*)(kt + kc * 512 + lane * 8);

#pragma unroll 2
    for (int t = 0; t < 16; ++t) {
        const int cur = t & 1;
        if (t < 15) {
#pragma unroll
            for (int kc = 0; kc < 4; ++kc)
                akf[cur ^ 1][kc] = *(const bf16x8*)(kt + (size_t)(t + 1) * 2048 + kc * 512 + lane * 8);
        }
#pragma unroll
        for (int ct = 0; ct < 2; ++ct)
#pragma unroll
            for (int kcs = 0; kcs < 4; ++kcs)
                avf[ct][kcs] = *(const bf16x4*)(vt + (size_t)t * 2048 + kcs * 512 + hi * 256 + ct * 128 + il * 4);

#pragma unroll
        for (int qs = 0; qs < 2; ++qs) {
            // S^T = K Q^T for this Q-subtile (first MFMA consumes zf as C)
            __builtin_amdgcn_s_setprio(1);
            f32x16 st = mfma32(akf[cur][0], bqf[qs][0], zf);
#pragma unroll
            for (int kc = 1; kc < 4; ++kc) st = mfma32(akf[cur][kc], bqf[qs][kc], st);
            __builtin_amdgcn_s_setprio(0);

            // p = exp2(S') (no shift; constant cancels in O/l).
            // regs 4g..4g+3 = B-frag of PV k-chunk g.
            bf16x4 bp[4];
#pragma unroll
            for (int g = 0; g < 4; ++g) {
                bp[g][0] = (__bf16)fast_exp2(st[g * 4 + 0]);
                bp[g][1] = (__bf16)fast_exp2(st[g * 4 + 1]);
                bp[g][2] = (__bf16)fast_exp2(st[g * 4 + 2]);
                bp[g][3] = (__bf16)fast_exp2(st[g * 4 + 3]);
            }

            // row-sum of P via ones-A MFMA: lacc[r][il] = sum_j P^T[j][il]
            // (all rows identical, both hi halves get the full column sum)
            __builtin_amdgcn_s_setprio(1);
            f32x16 lacc = pv_mfma(ones4, bp[0], zf);
#pragma unroll
            for (int g = 1; g < 4; ++g) lacc = pv_mfma(ones4, bp[g], lacc);

            // O^T += V P^T
#pragma unroll
            for (int ct = 0; ct < 2; ++ct)
#pragma unroll
                for (int g = 0; g < 4; ++g)
                    accO[qs * 2 + ct] = pv_mfma(avf[ct][g], bp[g], accO[qs * 2 + ct]);
            __builtin_amdgcn_s_setprio(0);

            lsum[qs] += lacc[0];
        }
    }

    // lsum already holds the full per-column(i) sum (MFMA broadcast both
    // halves); no cross-lane reduce needed.
    if (hi == 0) {
        lds_l[wave][il]      = lsum[0];
        lds_l[wave][32 + il] = lsum[1];
    }

    // ---- cross-wave combine: 3-slot LDS tree ----
    // accO element (qs,ct,r) -> c = ct*32+(r&3)+8*(r>>2)+4*hi, i = qs*32+il
#define ACC_STORE(SLOT)                                                        \
    do {                                                                       \
        _Pragma("unroll")                                                      \
        for (int qs = 0; qs < 2; ++qs)                                         \
            _Pragma("unroll")                                                  \
            for (int ct = 0; ct < 2; ++ct)                                     \
                _Pragma("unroll")                                              \
                for (int r = 0; r < 16; ++r)                                   \
                    lds_acc[SLOT][ct * 32 + (r & 3) + 8 * (r >> 2) + 4 * hi][qs * 32 + il] = accO[qs * 2 + ct][r]; \
    } while (0)
#define ACC_LOAD(SLOT)                                                         \
    do {                                                                       \
        _Pragma("unroll")                                                      \
        for (int qs = 0; qs < 2; ++qs)                                         \
            _Pragma("unroll")                                                  \
            for (int ct = 0; ct < 2; ++ct)                                     \
                _Pragma("unroll")                                              \
                for (int r = 0; r < 16; ++r)                                   \
                    accO[qs * 2 + ct][r] += lds_acc[SLOT][ct * 32 + (r & 3) + 8 * (r >> 2) + 4 * hi][qs * 32 + il]; \
    } while (0)

    if (wave >= 5) ACC_STORE(wave - 5);                 // w5->0, w6->1, w7->2
    __syncthreads();
    if (wave >= 1 && wave <= 3) ACC_LOAD(wave - 1);     // w1+=w5, w2+=w6, w3+=w7
    __syncthreads();
    if (wave >= 2 && wave <= 4) ACC_STORE(wave - 2);    // w2->0, w3->1, w4->2
    __syncthreads();
    if (wave <= 1) ACC_LOAD(wave);                      // w0+=(w2+w6), w1+=(w3+w7)
    if (wave == 0) ACC_LOAD(2);                         // w0+=w4
    __syncthreads();
    if (wave == 1) ACC_STORE(0);                        // (w1+w5+w3+w7) -> s0
    __syncthreads();
    if (wave == 0) { ACC_LOAD(0); ACC_STORE(0); }       // total -> s0
    __syncthreads();
#undef ACC_STORE
#undef ACC_LOAD

    // ---- epilogue: out = gamma*O/l + x1 ----
    const float g = gamma[0];
    {
        const int c  = tid >> 3;           // 0..63
        const int i8 = (tid & 7) * 8;      // 0..56
        float lv[8];
#pragma unroll
        for (int e = 0; e < 8; ++e) {
            float s = 0.f;
#pragma unroll
            for (int w = 0; w < 8; ++w) s += lds_l[w][i8 + e];
            lv[e] = s;
        }
        const size_t idx = ((size_t)b * C + c) * N + ibase + i8;
        f32x4 o0 = *(const f32x4*)&lds_acc[0][c][i8];
        f32x4 o1 = *(const f32x4*)&lds_acc[0][c][i8 + 4];
        f32x4 x0 = *(const f32x4*)(x1 + idx);
        f32x4 x4 = *(const f32x4*)(x1 + idx + 4);
        f32x4 r0, r1;
#pragma unroll
        for (int e = 0; e < 4; ++e) {
            r0[e] = g * o0[e] / lv[e] + x0[e];
            r1[e] = g * o1[e] / lv[4 + e] + x4[e];
        }
        *(f32x4*)(out + idx) = r0;
        *(f32x4*)(out + idx + 4) = r1;
    }
}

// ---------------------------------------------------------------------------
extern "C" void kernel_launch(void* const* d_in, const int* in_sizes, int n_in,
                              void* d_out, int out_size, void* d_ws, size_t ws_size,
                              hipStream_t stream) {
    const float* x1    = (const float*)d_in[0];
    const float* x2    = (const float*)d_in[1];
    const float* wq    = (const float*)d_in[2];
    const float* bqv   = (const float*)d_in[3];
    const float* wk    = (const float*)d_in[4];
    const float* bkv   = (const float*)d_in[5];
    const float* wv    = (const float*)d_in[6];
    const float* bvv   = (const float*)d_in[7];
    const float* gamma = (const float*)d_in[8];
    float* out = (float*)d_out;

    __bf16* qws = (__bf16*)d_ws;                   // tiled Q, 2 MB
    __bf16* kws = qws + (size_t)4 * 128 * 2048;    // tiled K, 2 MB
    __bf16* vws = kws + (size_t)4 * 128 * 2048;    // tiled V, 2 MB

    qkv_kernel<<<768, 256, 0, stream>>>(x1, x2, wq, bqv, wk, bkv, wv, bvv, qws, kws, vws);
    attn_kernel<<<256, 512, 0, stream>>>(qws, kws, vws, x1, gamma, out);
}

// Round 3
// 103.973 us; speedup vs baseline: 1.0242x; 1.0242x over previous
//
#include <hip/hip_runtime.h>
#include <cstdint>
#include <cstddef>

// ---------------------------------------------------------------------------
// ChannelWiseCrossAttention: B=4, C=64, H=W=64, N=4096
// Workspace layouts are MFMA-fragment-major (wave-contiguous loads):
//   Q,K per (b, 32-row tile): [kc(4)][hi(2)][il(32)][e(8)]  (2048 elems)
//     element (row il, c = kc*16+hi*8+e)
//   V  per (b, 32-col tile):  [kcs(4)][vh(2)][il(32)][ct(2)][e(4)] (2048 elems)
//     element (c = ct*32+il, j = kcs*8+vh*4+e)  -- 16B bf16x8 = both ct frags
// qkv: ONE 768-block kernel; kind = bid>>8 in {Q,K,V}; block = 64 pixels of
//   one projection.
// attn (round 11, resubmit after infra failure): 512 blocks x 8 waves;
//   block = (b, 32-row Q-tile); wave w owns j-tiles [w*16, w*16+16).
//   32-row tiles halve per-wave VGPR state (accO 2x f32x16, single-buffered
//   K) to fit 128 VGPR -> __launch_bounds__(512,4) -> 2 blocks/CU,
//   4 waves/SIMD (2x occupancy vs the 64-row version: latency-stall fix).
//   V loads are 4x bf16x8 (was 8x bf16x4). lsum via VALU adds + shfl_xor.
// ---------------------------------------------------------------------------

typedef __bf16 bf16x2 __attribute__((ext_vector_type(2)));
typedef __bf16 bf16x4 __attribute__((ext_vector_type(4)));
typedef __bf16 bf16x8 __attribute__((ext_vector_type(8)));
typedef float  f32x4  __attribute__((ext_vector_type(4)));
typedef float  f32x16 __attribute__((ext_vector_type(16)));
typedef short  s16x4  __attribute__((ext_vector_type(4)));

constexpr int C = 64;
constexpr int N = 4096;
constexpr float LOG2E = 1.44269504088896340736f;

static __device__ __forceinline__ f32x4 mfma16(bf16x8 a, bf16x8 b, f32x4 c) {
    return __builtin_amdgcn_mfma_f32_16x16x32_bf16(a, b, c, 0, 0, 0);
}
static __device__ __forceinline__ f32x16 mfma32(bf16x8 a, bf16x8 b, f32x16 c) {
    return __builtin_amdgcn_mfma_f32_32x32x16_bf16(a, b, c, 0, 0, 0);
}
// 32x32x8 bf16 (A/B = 4 bf16, k = 4*hi + j). Native if available, else
// zero-padded 32x32x16 (logical k at slot j in both operands).
static __device__ __forceinline__ f32x16 pv_mfma(bf16x4 a, bf16x4 b, f32x16 c) {
#if __has_builtin(__builtin_amdgcn_mfma_f32_32x32x8bf16_1k)
    union U { bf16x4 h; s16x4 s; };
    U ua; ua.h = a;
    U ub; ub.h = b;
    return __builtin_amdgcn_mfma_f32_32x32x8bf16_1k(ua.s, ub.s, c, 0, 0, 0);
#else
    const __bf16 z = (__bf16)0.0f;
    bf16x8 a8 = {a[0], a[1], a[2], a[3], z, z, z, z};
    bf16x8 b8 = {b[0], b[1], b[2], b[3], z, z, z, z};
    return __builtin_amdgcn_mfma_f32_32x32x16_bf16(a8, b8, c, 0, 0, 0);
#endif
}
static __device__ __forceinline__ float fast_exp2(float x) {
#if __has_builtin(__builtin_amdgcn_exp2f)
    return __builtin_amdgcn_exp2f(x);
#else
    return exp2f(x);
#endif
}

// ---------------------------------------------------------------------------
// QKV conv, 3-way split. grid = 768 x 256 thr. kind = bid>>8: 0=Q, 1=K, 2=V.
// Each block: one projection, 64 pixels, 4 waves x 16 pixels.
//   Q,K: D[n][o] = X^T W^T (A = x frag, B = W row-major from LDS)
//   V  : D[o][n] = W X     (A = W row-major from LDS, B = x frag)
// Results round-trip a padded LDS transpose so all global stores are 16B.
// ---------------------------------------------------------------------------
__global__ __launch_bounds__(256) void qkv_kernel(
    const float* __restrict__ x1, const float* __restrict__ x2,
    const float* __restrict__ wq, const float* __restrict__ bq,
    const float* __restrict__ wk, const float* __restrict__ bk,
    const float* __restrict__ wv, const float* __restrict__ bv,
    __bf16* __restrict__ qo, __bf16* __restrict__ ko, __bf16* __restrict__ vo)
{
    __shared__ __bf16 wl[64][72];     // W row-major, 9 KB
    __shared__ __bf16 tout[64][72];   // [pixel][o] transpose buffer, 9 KB

    const int bid  = blockIdx.x;
    const int kind = bid >> 8;                 // 0=Q, 1=K, 2=V (block-uniform)
    const int pg   = bid & 255;
    const int b     = pg >> 6;
    const int nbase = (pg & 63) * 64;
    const int tid   = threadIdx.x;

    const float* wsel = kind == 0 ? wq : (kind == 1 ? wk : wv);
    const float* bsel = kind == 0 ? bq : (kind == 1 ? bk : bv);
    const float* xsel = kind == 0 ? x1 : x2;
    __bf16*      osel = kind == 0 ? qo : (kind == 1 ? ko : vo);

    // ---- stage W (64x64 fp32 -> bf16 LDS) ----
#pragma unroll
    for (int i = 0; i < 4; ++i) {
        int idx = i * 256 + tid;
        int row = idx >> 4, c4 = (idx & 15) * 4;
        float4 a = *(const float4*)(wsel + row * 64 + c4);
        bf16x4 h = {(__bf16)a.x, (__bf16)a.y, (__bf16)a.z, (__bf16)a.w};
        *(bf16x4*)&wl[row][c4] = h;
    }
    __syncthreads();

    const int wave = tid >> 6, lane = tid & 63;
    const int l = lane & 15, qd = lane >> 4;
    const int p = nbase + wave * 16 + l;       // this lane's pixel

    // x fragment: A/B[k=c][pixel p], c = ks*32 + qd*8 + j
    const float* xb = xsel + (size_t)b * C * N + p;
    bf16x8 ax[2];
#pragma unroll
    for (int ks = 0; ks < 2; ++ks)
#pragma unroll
        for (int j = 0; j < 8; ++j)
            ax[ks][j] = (__bf16)xb[(size_t)(ks * 32 + qd * 8 + j) * N];

    if (kind < 2) {
        // ---- Q/K: D[pixel][o] ----
        const float scale = kind == 0 ? LOG2E : 1.0f;
#pragma unroll
        for (int ot = 0; ot < 4; ++ot) {
            const float bb = bsel[ot * 16 + l];
            f32x4 acc = {bb, bb, bb, bb};
#pragma unroll
            for (int ks = 0; ks < 2; ++ks) {
                bf16x8 bw = *(const bf16x8*)&wl[ot * 16 + l][ks * 32 + qd * 8];
                acc = mfma16(ax[ks], bw, acc);
            }
#pragma unroll
            for (int r = 0; r < 4; ++r) {
                int px = wave * 16 + qd * 4 + r;
                tout[px][ot * 16 + l] = (__bf16)(acc[r] * scale);
            }
        }
        __syncthreads();

        // ---- drain: frag-major 16B contiguous stores ----
        const int tile = tid >> 7, t7 = tid & 127;
        const int kc = t7 >> 5, h2 = (t7 >> 4) & 1, ilp = (t7 & 15) * 2;
        const size_t tb = ((size_t)b * 128 + (nbase >> 5) + tile) * 2048;
        const size_t off = tb + kc * 512 + h2 * 256 + ilp * 8;
        bf16x8 ra = *(const bf16x8*)&tout[tile * 32 + ilp][kc * 16 + h2 * 8];
        bf16x8 rb = *(const bf16x8*)&tout[tile * 32 + ilp + 1][kc * 16 + h2 * 8];
        *(bf16x8*)&osel[off]     = ra;
        *(bf16x8*)&osel[off + 8] = rb;
    } else {
        // ---- V: D[o][pixel] -> tout[pixel][o] ----
#pragma unroll
        for (int ct = 0; ct < 4; ++ct) {
            f32x4 acc;
#pragma unroll
            for (int r = 0; r < 4; ++r) acc[r] = bsel[ct * 16 + qd * 4 + r];
#pragma unroll
            for (int ks = 0; ks < 2; ++ks) {
                bf16x8 aw = *(const bf16x8*)&wl[ct * 16 + l][ks * 32 + qd * 8];
                acc = mfma16(aw, ax[ks], acc);
            }
            bf16x4 pk = {(__bf16)acc[0], (__bf16)acc[1], (__bf16)acc[2], (__bf16)acc[3]};
            *(bf16x4*)&tout[wave * 16 + l][ct * 16 + qd * 4] = pk;
        }
        __syncthreads();

        // ---- drain: [g][vh][il][ct][e4], 16B contiguous stores ----
        // element (c = ct*32+il, j = g*8+vh*4+e) at g*512+vh*256+il*8+ct*4+e
        const int tile = tid >> 7, t7 = tid & 127;
        const int g = t7 >> 5, vh = (t7 >> 4) & 1, il0 = (t7 & 15) * 2;
        const int pxb = tile * 32 + g * 8 + vh * 4;   // pixel row of e=0
        bf16x8 oA, oB;
#pragma unroll
        for (int ct = 0; ct < 2; ++ct)
#pragma unroll
            for (int e = 0; e < 4; ++e) {
                bf16x2 pr = *(const bf16x2*)&tout[pxb + e][ct * 32 + il0];
                oA[ct * 4 + e] = pr[0];
                oB[ct * 4 + e] = pr[1];
            }
        const size_t tb = ((size_t)b * 128 + (nbase >> 5) + tile) * 2048;
        const size_t off = tb + g * 512 + vh * 256 + il0 * 8;
        *(bf16x8*)&osel[off]     = oA;   // il0
        *(bf16x8*)&osel[off + 8] = oB;   // il0+1
    }
}

// ---------------------------------------------------------------------------
// Attention. grid = 512 blocks x 512 thr (8 waves).
// Block = (b, 32-row Q-tile); wave w owns j-tiles [w*16, w*16+16).
// 32x32x16: A/B 8 elems k=(lane>>5)*8+j; C/D row=(r&3)+8*(r>>2)+4*hi, col=il.
// Per-wave state budgeted <=128 VGPR for 4 waves/SIMD (2 blocks/CU).
// ---------------------------------------------------------------------------
__global__ __launch_bounds__(512, 4) void attn_kernel(
    const __bf16* __restrict__ qg, const __bf16* __restrict__ kg,
    const __bf16* __restrict__ vg, const float* __restrict__ x1,
    const float* __restrict__ gamma, float* __restrict__ out)
{
    __shared__ float lds_acc[3][64][32];   // 3 combine slots, 24 KB, [c][i]
    __shared__ float lds_l[8][32];         // per-wave lsum partials, [w][i]

    const int bid = blockIdx.x;                      // 0..511
    const int xcd = bid & 7;
    const int b   = xcd >> 1;                        // one batch per XCD pair
    const int rt  = ((bid >> 3) << 1) | (xcd & 1);   // 0..127 (32-row tile)
    const int ibase = rt * 32;

    const int tid  = threadIdx.x;
    const int wave = tid >> 6, lane = tid & 63;
    const int il = lane & 31, hi = lane >> 5;

    const __bf16* qt = qg + ((size_t)b * 128 + rt) * 2048;
    const __bf16* kt = kg + (size_t)b * 128 * 2048 + (size_t)(wave * 16) * 2048;
    const __bf16* vt = vg + (size_t)b * 128 * 2048 + (size_t)(wave * 16) * 2048;

    // Q B-frags for this 32-row tile: 1 KB contiguous per load
    bf16x8 bqf[4];
#pragma unroll
    for (int kc = 0; kc < 4; ++kc)
        bqf[kc] = *(const bf16x8*)(qt + kc * 512 + lane * 8);

    f32x16 accO[2];   // [ct]
#pragma unroll
    for (int a = 0; a < 2; ++a)
#pragma unroll
        for (int r = 0; r < 16; ++r) accO[a][r] = 0.f;
    float lsum = 0.f;

#pragma unroll 1
    for (int t = 0; t < 16; ++t) {
        // K frags (16B each) then V frags (16B each, both ct halves)
        bf16x8 ak[4], av[4];
#pragma unroll
        for (int kc = 0; kc < 4; ++kc)
            ak[kc] = *(const bf16x8*)(kt + (size_t)t * 2048 + kc * 512 + lane * 8);
#pragma unroll
        for (int g = 0; g < 4; ++g)
            av[g] = *(const bf16x8*)(vt + (size_t)t * 2048 + g * 512 + hi * 256 + il * 8);

        // S^T = K Q^T
        f32x16 st;
#pragma unroll
        for (int r = 0; r < 16; ++r) st[r] = 0.f;
#pragma unroll
        for (int kc = 0; kc < 4; ++kc) st = mfma32(ak[kc], bqf[kc], st);

        // p = exp2(S') (no shift; constant cancels in O/l).
        bf16x4 bp[4];
        float lp0 = 0.f, lp1 = 0.f, lp2 = 0.f, lp3 = 0.f;
#pragma unroll
        for (int g = 0; g < 4; ++g) {
            float p0 = fast_exp2(st[g * 4 + 0]);
            float p1 = fast_exp2(st[g * 4 + 1]);
            float p2 = fast_exp2(st[g * 4 + 2]);
            float p3 = fast_exp2(st[g * 4 + 3]);
            lp0 += p0; lp1 += p1; lp2 += p2; lp3 += p3;
            bp[g][0] = (__bf16)p0; bp[g][1] = (__bf16)p1;
            bp[g][2] = (__bf16)p2; bp[g][3] = (__bf16)p3;
        }
        lsum += (lp0 + lp1) + (lp2 + lp3);

        // O^T += V P^T  (A-frags = lo/hi halves of av)
#pragma unroll
        for (int g = 0; g < 4; ++g) {
            bf16x4 v0 = __builtin_shufflevector(av[g], av[g], 0, 1, 2, 3);
            bf16x4 v1 = __builtin_shufflevector(av[g], av[g], 4, 5, 6, 7);
            accO[0] = pv_mfma(v0, bp[g], accO[0]);
            accO[1] = pv_mfma(v1, bp[g], accO[1]);
        }
    }

    // per-lane lsum -> per-column(i) sum within wave (pair hi halves)
    lsum += __shfl_xor(lsum, 32);
    if (hi == 0) lds_l[wave][il] = lsum;

    // ---- cross-wave combine: 3-slot LDS tree ----
    // accO element (ct,r) -> c = ct*32+(r&3)+8*(r>>2)+4*hi, i = il
#define ACC_STORE(SLOT)                                                        \
    do {                                                                       \
        _Pragma("unroll")                                                      \
        for (int ct = 0; ct < 2; ++ct)                                         \
            _Pragma("unroll")                                                  \
            for (int r = 0; r < 16; ++r)                                       \
                lds_acc[SLOT][ct * 32 + (r & 3) + 8 * (r >> 2) + 4 * hi][il] = accO[ct][r]; \
    } while (0)
#define ACC_LOAD(SLOT)                                                         \
    do {                                                                       \
        _Pragma("unroll")                                                      \
        for (int ct = 0; ct < 2; ++ct)                                         \
            _Pragma("unroll")                                                  \
            for (int r = 0; r < 16; ++r)                                       \
                accO[ct][r] += lds_acc[SLOT][ct * 32 + (r & 3) + 8 * (r >> 2) + 4 * hi][il]; \
    } while (0)

    if (wave >= 5) ACC_STORE(wave - 5);                 // w5->0, w6->1, w7->2
    __syncthreads();
    if (wave >= 1 && wave <= 3) ACC_LOAD(wave - 1);     // w1+=w5, w2+=w6, w3+=w7
    __syncthreads();
    if (wave >= 2 && wave <= 4) ACC_STORE(wave - 2);    // w2->0, w3->1, w4->2
    __syncthreads();
    if (wave <= 1) ACC_LOAD(wave);                      // w0+=(w2+w6), w1+=(w3+w7)
    if (wave == 0) ACC_LOAD(2);                         // w0+=w4
    __syncthreads();
    if (wave == 1) ACC_STORE(0);                        // (w1+w5+w3+w7) -> s0
    __syncthreads();
    if (wave == 0) { ACC_LOAD(0); ACC_STORE(0); }       // total -> s0
    __syncthreads();
#undef ACC_STORE
#undef ACC_LOAD

    // ---- epilogue: out = gamma*O/l + x1 ----
    const float g = gamma[0];
    {
        const int c  = tid >> 3;           // 0..63
        const int i4 = (tid & 7) * 4;      // 0..28
        f32x4 lv = {0.f, 0.f, 0.f, 0.f};
#pragma unroll
        for (int w = 0; w < 8; ++w) {
            f32x4 lw = *(const f32x4*)&lds_l[w][i4];
#pragma unroll
            for (int e = 0; e < 4; ++e) lv[e] += lw[e];
        }
        const size_t idx = ((size_t)b * C + c) * N + ibase + i4;
        f32x4 o0 = *(const f32x4*)&lds_acc[0][c][i4];
        f32x4 x0 = *(const f32x4*)(x1 + idx);
        f32x4 r0;
#pragma unroll
        for (int e = 0; e < 4; ++e)
            r0[e] = g * o0[e] / lv[e] + x0[e];
        *(f32x4*)(out + idx) = r0;
    }
}

// ---------------------------------------------------------------------------
extern "C" void kernel_launch(void* const* d_in, const int* in_sizes, int n_in,
                              void* d_out, int out_size, void* d_ws, size_t ws_size,
                              hipStream_t stream) {
    const float* x1    = (const float*)d_in[0];
    const float* x2    = (const float*)d_in[1];
    const float* wq    = (const float*)d_in[2];
    const float* bqv   = (const float*)d_in[3];
    const float* wk    = (const float*)d_in[4];
    const float* bkv   = (const float*)d_in[5];
    const float* wv    = (const float*)d_in[6];
    const float* bvv   = (const float*)d_in[7];
    const float* gamma = (const float*)d_in[8];
    float* out = (float*)d_out;

    __bf16* qws = (__bf16*)d_ws;                   // tiled Q, 2 MB
    __bf16* kws = qws + (size_t)4 * 128 * 2048;    // tiled K, 2 MB
    __bf16* vws = kws + (size_t)4 * 128 * 2048;    // tiled V, 2 MB

    qkv_kernel<<<768, 256, 0, stream>>>(x1, x2, wq, bqv, wk, bkv, wv, bvv, qws, kws, vws);
    attn_kernel<<<512, 512, 0, stream>>>(qws, kws, vws, x1, gamma, out);
}

// Round 4
// 100.062 us; speedup vs baseline: 1.0643x; 1.0391x over previous
//
#include <hip/hip_runtime.h>
#include <cstdint>
#include <cstddef>

// ---------------------------------------------------------------------------
// ChannelWiseCrossAttention: B=4, C=64, H=W=64, N=4096
// Workspace layouts are MFMA-fragment-major (wave-contiguous loads):
//   Q,K per (b, 32-row tile): [kc(4)][hi(2)][il(32)][e(8)]  (2048 elems)
//     element (row il, c = kc*16+hi*8+e)
//   V  per (b, 32-col tile):  [G(2)][vh(2)][il(32)][ct(2)][e(8)] (2048 elems)
//     element (c = ct*32+il, j = G*16+vh*8+e)  -- A-frag-major for 32x32x16
// attn (round 12): 256 blocks x 8 waves; block = (b, 64-row Q-tile = 2
//   subtiles); wave w owns j-tiles [w*16, w*16+16).  L2-BW theory: traffic =
//   (4096/R)*4MB for R-row tiles; R=64 halves round-11's 512 MB.
//   PV now FULL-RATE 32x32x16: P repacked to k=16 B-frags via bf16x2 packs +
//   v_permlane32_swap_b32 (each hi-half receives the j-rows it lacks), V
//   A-frags are 16B contiguous in the new layout. 8 mfma32/t instead of 16
//   half-rate 32x32x8.
// ---------------------------------------------------------------------------

typedef __bf16 bf16x2 __attribute__((ext_vector_type(2)));
typedef __bf16 bf16x4 __attribute__((ext_vector_type(4)));
typedef __bf16 bf16x8 __attribute__((ext_vector_type(8)));
typedef float  f32x4  __attribute__((ext_vector_type(4)));
typedef float  f32x16 __attribute__((ext_vector_type(16)));

constexpr int C = 64;
constexpr int N = 4096;
constexpr float LOG2E = 1.44269504088896340736f;

static __device__ __forceinline__ f32x4 mfma16(bf16x8 a, bf16x8 b, f32x4 c) {
    return __builtin_amdgcn_mfma_f32_16x16x32_bf16(a, b, c, 0, 0, 0);
}
static __device__ __forceinline__ f32x16 mfma32(bf16x8 a, bf16x8 b, f32x16 c) {
    return __builtin_amdgcn_mfma_f32_32x32x16_bf16(a, b, c, 0, 0, 0);
}
static __device__ __forceinline__ float fast_exp2(float x) {
#if __has_builtin(__builtin_amdgcn_exp2f)
    return __builtin_amdgcn_exp2f(x);
#else
    return exp2f(x);
#endif
}
static __device__ __forceinline__ uint32_t pack2(float a, float b) {
    union { uint32_t u; bf16x2 h; } w;
    w.h = bf16x2{(__bf16)a, (__bf16)b};
    return w.u;
}

// ---------------------------------------------------------------------------
// QKV conv, 3-way split. grid = 768 x 256 thr. kind = bid>>8: 0=Q, 1=K, 2=V.
// Each block: one projection, 64 pixels, 4 waves x 16 pixels.
//   Q,K: D[n][o] = X^T W^T (A = x frag, B = W row-major from LDS)
//   V  : D[o][n] = W X     (A = W row-major from LDS, B = x frag)
// Results round-trip a padded LDS transpose so all global stores are 16B.
// ---------------------------------------------------------------------------
__global__ __launch_bounds__(256) void qkv_kernel(
    const float* __restrict__ x1, const float* __restrict__ x2,
    const float* __restrict__ wq, const float* __restrict__ bq,
    const float* __restrict__ wk, const float* __restrict__ bk,
    const float* __restrict__ wv, const float* __restrict__ bv,
    __bf16* __restrict__ qo, __bf16* __restrict__ ko, __bf16* __restrict__ vo)
{
    __shared__ __bf16 wl[64][72];     // W row-major, 9 KB
    __shared__ __bf16 tout[64][72];   // [pixel][o] transpose buffer, 9 KB

    const int bid  = blockIdx.x;
    const int kind = bid >> 8;                 // 0=Q, 1=K, 2=V (block-uniform)
    const int pg   = bid & 255;
    const int b     = pg >> 6;
    const int nbase = (pg & 63) * 64;
    const int tid   = threadIdx.x;

    const float* wsel = kind == 0 ? wq : (kind == 1 ? wk : wv);
    const float* bsel = kind == 0 ? bq : (kind == 1 ? bk : bv);
    const float* xsel = kind == 0 ? x1 : x2;
    __bf16*      osel = kind == 0 ? qo : (kind == 1 ? ko : vo);

    // ---- stage W (64x64 fp32 -> bf16 LDS) ----
#pragma unroll
    for (int i = 0; i < 4; ++i) {
        int idx = i * 256 + tid;
        int row = idx >> 4, c4 = (idx & 15) * 4;
        float4 a = *(const float4*)(wsel + row * 64 + c4);
        bf16x4 h = {(__bf16)a.x, (__bf16)a.y, (__bf16)a.z, (__bf16)a.w};
        *(bf16x4*)&wl[row][c4] = h;
    }
    __syncthreads();

    const int wave = tid >> 6, lane = tid & 63;
    const int l = lane & 15, qd = lane >> 4;
    const int p = nbase + wave * 16 + l;       // this lane's pixel

    // x fragment: A/B[k=c][pixel p], c = ks*32 + qd*8 + j
    const float* xb = xsel + (size_t)b * C * N + p;
    bf16x8 ax[2];
#pragma unroll
    for (int ks = 0; ks < 2; ++ks)
#pragma unroll
        for (int j = 0; j < 8; ++j)
            ax[ks][j] = (__bf16)xb[(size_t)(ks * 32 + qd * 8 + j) * N];

    if (kind < 2) {
        // ---- Q/K: D[pixel][o] ----
        const float scale = kind == 0 ? LOG2E : 1.0f;
#pragma unroll
        for (int ot = 0; ot < 4; ++ot) {
            const float bb = bsel[ot * 16 + l];
            f32x4 acc = {bb, bb, bb, bb};
#pragma unroll
            for (int ks = 0; ks < 2; ++ks) {
                bf16x8 bw = *(const bf16x8*)&wl[ot * 16 + l][ks * 32 + qd * 8];
                acc = mfma16(ax[ks], bw, acc);
            }
#pragma unroll
            for (int r = 0; r < 4; ++r) {
                int px = wave * 16 + qd * 4 + r;
                tout[px][ot * 16 + l] = (__bf16)(acc[r] * scale);
            }
        }
        __syncthreads();

        // ---- drain: frag-major 16B contiguous stores ----
        const int tile = tid >> 7, t7 = tid & 127;
        const int kc = t7 >> 5, h2 = (t7 >> 4) & 1, ilp = (t7 & 15) * 2;
        const size_t tb = ((size_t)b * 128 + (nbase >> 5) + tile) * 2048;
        const size_t off = tb + kc * 512 + h2 * 256 + ilp * 8;
        bf16x8 ra = *(const bf16x8*)&tout[tile * 32 + ilp][kc * 16 + h2 * 8];
        bf16x8 rb = *(const bf16x8*)&tout[tile * 32 + ilp + 1][kc * 16 + h2 * 8];
        *(bf16x8*)&osel[off]     = ra;
        *(bf16x8*)&osel[off + 8] = rb;
    } else {
        // ---- V: D[o][pixel] -> tout[pixel][o] ----
#pragma unroll
        for (int ct = 0; ct < 4; ++ct) {
            f32x4 acc;
#pragma unroll
            for (int r = 0; r < 4; ++r) acc[r] = bsel[ct * 16 + qd * 4 + r];
#pragma unroll
            for (int ks = 0; ks < 2; ++ks) {
                bf16x8 aw = *(const bf16x8*)&wl[ct * 16 + l][ks * 32 + qd * 8];
                acc = mfma16(aw, ax[ks], acc);
            }
            bf16x4 pk = {(__bf16)acc[0], (__bf16)acc[1], (__bf16)acc[2], (__bf16)acc[3]};
            *(bf16x4*)&tout[wave * 16 + l][ct * 16 + qd * 4] = pk;
        }
        __syncthreads();

        // ---- drain: [G][vh][il][ct][e8], two 16B stores per thread ----
        // element (c = ct*32+il, j = G*16+vh*8+e) at G*1024+vh*512+il*16+ct*8+e
        const int tile = tid >> 7, t7 = tid & 127;
        const int G = t7 >> 6, vh = (t7 >> 5) & 1, il = t7 & 31;
        const int pxb = tile * 32 + G * 16 + vh * 8;   // pixel row of e=0
        bf16x8 oA, oB;
#pragma unroll
        for (int e = 0; e < 8; ++e) {
            oA[e] = tout[pxb + e][il];        // ct = 0
            oB[e] = tout[pxb + e][32 + il];   // ct = 1
        }
        const size_t tb = ((size_t)b * 128 + (nbase >> 5) + tile) * 2048;
        const size_t off = tb + G * 1024 + vh * 512 + (size_t)il * 16;
        *(bf16x8*)&osel[off]     = oA;
        *(bf16x8*)&osel[off + 8] = oB;
    }
}

// ---------------------------------------------------------------------------
// Attention. grid = 256 blocks x 512 thr (8 waves).
// Block = (b, 64-row Q-tile = 2 subtiles); wave w owns j-tiles [w*16,w*16+16).
// 32x32x16: A/B 8 elems k=(lane>>5)*8+j; C/D row=(r&3)+8*(r>>2)+4*hi, col=il.
// PV full-rate: P^T B-frags built by pairing exp2 outputs into bf16x2 words
// and exchanging halves with v_permlane32_swap_b32:
//   lane (il,hi) holds P^T[j=(r&3)+8*(r>>2)+4hi][il]; frag for k-chunk G needs
//   j = G*16+hi*8+{0..7}.  swap(pk(p0,p1), pk(p4,p5)) yields words 0,2; 
//   swap(pk(p2,p3), pk(p6,p7)) yields words 1,3.
// ---------------------------------------------------------------------------
__global__ __launch_bounds__(512, 2) void attn_kernel(
    const __bf16* __restrict__ qg, const __bf16* __restrict__ kg,
    const __bf16* __restrict__ vg, const float* __restrict__ x1,
    const float* __restrict__ gamma, float* __restrict__ out)
{
    __shared__ float lds_acc[3][64][64];   // 3 combine slots, 48 KB, [c][i]
    __shared__ float lds_l[8][64];         // per-wave lsum partials, [w][i]

    const int bid = blockIdx.x;                      // 0..255
    const int xcd = bid & 7;
    const int b   = xcd >> 1;
    const int rt  = ((bid >> 3) << 1) | (xcd & 1);   // 0..63 (64-row tile)
    const int ibase = rt * 64;

    const int tid  = threadIdx.x;
    const int wave = tid >> 6, lane = tid & 63;
    const int il = lane & 31, hi = lane >> 5;

    const __bf16* qt = qg + ((size_t)b * 128 + rt * 2) * 2048;
    const __bf16* kt = kg + (size_t)b * 128 * 2048 + (size_t)(wave * 16) * 2048;
    const __bf16* vt = vg + (size_t)b * 128 * 2048 + (size_t)(wave * 16) * 2048;

    // Q B-frags for both 32-row subtiles: 1 KB contiguous per load
    bf16x8 bqf[2][4];
#pragma unroll
    for (int qs = 0; qs < 2; ++qs)
#pragma unroll
        for (int kc = 0; kc < 4; ++kc)
            bqf[qs][kc] = *(const bf16x8*)(qt + qs * 2048 + kc * 512 + lane * 8);

    f32x16 accO[4];   // [qs*2 + ct]
#pragma unroll
    for (int a = 0; a < 4; ++a)
#pragma unroll
        for (int r = 0; r < 16; ++r) accO[a][r] = 0.f;
    float lsum[2] = {0.f, 0.f};

    bf16x8 akf[2][4];   // K frags, double-buffered

#pragma unroll
    for (int kc = 0; kc < 4; ++kc)
        akf[0][kc] = *(const bf16x8*)(kt + kc * 512 + lane * 8);

#pragma unroll 2
    for (int t = 0; t < 16; ++t) {
        const int cur = t & 1;
        if (t < 15) {
#pragma unroll
            for (int kc = 0; kc < 4; ++kc)
                akf[cur ^ 1][kc] = *(const bf16x8*)(kt + (size_t)(t + 1) * 2048 + kc * 512 + lane * 8);
        }
        // V A-frags for this tile: [ct][G], 16B contiguous each
        bf16x8 av[2][2];
#pragma unroll
        for (int ct = 0; ct < 2; ++ct)
#pragma unroll
            for (int G = 0; G < 2; ++G)
                av[ct][G] = *(const bf16x8*)(vt + (size_t)t * 2048 + G * 1024 + hi * 512 + il * 16 + ct * 8);

#pragma unroll
        for (int qs = 0; qs < 2; ++qs) {
            // S^T = K Q^T for this Q-subtile
            f32x16 st;
#pragma unroll
            for (int r = 0; r < 16; ++r) st[r] = 0.f;
#pragma unroll
            for (int kc = 0; kc < 4; ++kc) st = mfma32(akf[cur][kc], bqf[qs][kc], st);

            // p = exp2(S') (no shift; constant cancels in O/l).
            float p[16];
            float lp0 = 0.f, lp1 = 0.f;
#pragma unroll
            for (int r = 0; r < 16; r += 2) {
                p[r]     = fast_exp2(st[r]);
                p[r + 1] = fast_exp2(st[r + 1]);
                lp0 += p[r];
                lp1 += p[r + 1];
            }
            lsum[qs] += lp0 + lp1;

            // pack P^T into full-rate k=16 B-frags (2 chunks G=0,1)
            uint32_t a0 = pack2(p[0],  p[1]),  a1 = pack2(p[2],  p[3]);
            uint32_t b0 = pack2(p[4],  p[5]),  b1 = pack2(p[6],  p[7]);
            uint32_t c0 = pack2(p[8],  p[9]),  c1 = pack2(p[10], p[11]);
            uint32_t d0 = pack2(p[12], p[13]), d1 = pack2(p[14], p[15]);
            asm("v_permlane32_swap_b32 %0, %1" : "+v"(a0), "+v"(b0));
            asm("v_permlane32_swap_b32 %0, %1" : "+v"(a1), "+v"(b1));
            asm("v_permlane32_swap_b32 %0, %1" : "+v"(c0), "+v"(d0));
            asm("v_permlane32_swap_b32 %0, %1" : "+v"(c1), "+v"(d1));
            union F { uint32_t u[4]; bf16x8 v; } f0, f1;
            f0.u[0] = a0; f0.u[1] = a1; f0.u[2] = b0; f0.u[3] = b1;
            f1.u[0] = c0; f1.u[1] = c1; f1.u[2] = d0; f1.u[3] = d1;

            // O^T += V P^T (full-rate 32x32x16)
#pragma unroll
            for (int ct = 0; ct < 2; ++ct) {
                accO[qs * 2 + ct] = mfma32(av[ct][0], f0.v, accO[qs * 2 + ct]);
                accO[qs * 2 + ct] = mfma32(av[ct][1], f1.v, accO[qs * 2 + ct]);
            }
        }
    }

    // per-lane lsum -> per-column(i) sum within wave (pair hi halves)
#pragma unroll
    for (int qs = 0; qs < 2; ++qs) lsum[qs] += __shfl_xor(lsum[qs], 32);
    if (hi == 0) {
        lds_l[wave][il]      = lsum[0];
        lds_l[wave][32 + il] = lsum[1];
    }

    // ---- cross-wave combine: 3-slot LDS tree ----
    // accO element (qs,ct,r) -> c = ct*32+(r&3)+8*(r>>2)+4*hi, i = qs*32+il
#define ACC_STORE(SLOT)                                                        \
    do {                                                                       \
        _Pragma("unroll")                                                      \
        for (int qs = 0; qs < 2; ++qs)                                         \
            _Pragma("unroll")                                                  \
            for (int ct = 0; ct < 2; ++ct)                                     \
                _Pragma("unroll")                                              \
                for (int r = 0; r < 16; ++r)                                   \
                    lds_acc[SLOT][ct * 32 + (r & 3) + 8 * (r >> 2) + 4 * hi][qs * 32 + il] = accO[qs * 2 + ct][r]; \
    } while (0)
#define ACC_LOAD(SLOT)                                                         \
    do {                                                                       \
        _Pragma("unroll")                                                      \
        for (int qs = 0; qs < 2; ++qs)                                         \
            _Pragma("unroll")                                                  \
            for (int ct = 0; ct < 2; ++ct)                                     \
                _Pragma("unroll")                                              \
                for (int r = 0; r < 16; ++r)                                   \
                    accO[qs * 2 + ct][r] += lds_acc[SLOT][ct * 32 + (r & 3) + 8 * (r >> 2) + 4 * hi][qs * 32 + il]; \
    } while (0)

    if (wave >= 5) ACC_STORE(wave - 5);                 // w5->0, w6->1, w7->2
    __syncthreads();
    if (wave >= 1 && wave <= 3) ACC_LOAD(wave - 1);     // w1+=w5, w2+=w6, w3+=w7
    __syncthreads();
    if (wave >= 2 && wave <= 4) ACC_STORE(wave - 2);    // w2->0, w3->1, w4->2
    __syncthreads();
    if (wave <= 1) ACC_LOAD(wave);                      // w0+=(w2+w6), w1+=(w3+w7)
    if (wave == 0) ACC_LOAD(2);                         // w0+=w4
    __syncthreads();
    if (wave == 1) ACC_STORE(0);                        // (w1+w5+w3+w7) -> s0
    __syncthreads();
    if (wave == 0) { ACC_LOAD(0); ACC_STORE(0); }       // total -> s0
    __syncthreads();
#undef ACC_STORE
#undef ACC_LOAD

    // ---- epilogue: out = gamma*O/l + x1 ----
    const float g = gamma[0];
    {
        const int c  = tid >> 3;           // 0..63
        const int i8 = (tid & 7) * 8;      // 0..56
        float lv[8];
#pragma unroll
        for (int e = 0; e < 8; ++e) {
            float s = 0.f;
#pragma unroll
            for (int w = 0; w < 8; ++w) s += lds_l[w][i8 + e];
            lv[e] = s;
        }
        const size_t idx = ((size_t)b * C + c) * N + ibase + i8;
        f32x4 o0 = *(const f32x4*)&lds_acc[0][c][i8];
        f32x4 o1 = *(const f32x4*)&lds_acc[0][c][i8 + 4];
        f32x4 x0 = *(const f32x4*)(x1 + idx);
        f32x4 x4 = *(const f32x4*)(x1 + idx + 4);
        f32x4 r0, r1;
#pragma unroll
        for (int e = 0; e < 4; ++e) {
            r0[e] = g * o0[e] / lv[e] + x0[e];
            r1[e] = g * o1[e] / lv[4 + e] + x4[e];
        }
        *(f32x4*)(out + idx) = r0;
        *(f32x4*)(out + idx + 4) = r1;
    }
}

// ---------------------------------------------------------------------------
extern "C" void kernel_launch(void* const* d_in, const int* in_sizes, int n_in,
                              void* d_out, int out_size, void* d_ws, size_t ws_size,
                              hipStream_t stream) {
    const float* x1    = (const float*)d_in[0];
    const float* x2    = (const float*)d_in[1];
    const float* wq    = (const float*)d_in[2];
    const float* bqv   = (const float*)d_in[3];
    const float* wk    = (const float*)d_in[4];
    const float* bkv   = (const float*)d_in[5];
    const float* wv    = (const float*)d_in[6];
    const float* bvv   = (const float*)d_in[7];
    const float* gamma = (const float*)d_in[8];
    float* out = (float*)d_out;

    __bf16* qws = (__bf16*)d_ws;                   // tiled Q, 2 MB
    __bf16* kws = qws + (size_t)4 * 128 * 2048;    // tiled K, 2 MB
    __bf16* vws = kws + (size_t)4 * 128 * 2048;    // tiled V, 2 MB

    qkv_kernel<<<768, 256, 0, stream>>>(x1, x2, wq, bqv, wk, bkv, wv, bvv, qws, kws, vws);
    attn_kernel<<<256, 512, 0, stream>>>(qws, kws, vws, x1, gamma, out);
}

// Round 5
// 98.453 us; speedup vs baseline: 1.0817x; 1.0163x over previous
//
#include <hip/hip_runtime.h>
#include <cstdint>
#include <cstddef>

// ---------------------------------------------------------------------------
// ChannelWiseCrossAttention: B=4, C=64, H=W=64, N=4096
// Workspace layouts are MFMA-fragment-major (wave-contiguous loads):
//   Q,K per (b, 32-row tile): [kc(4)][hi(2)][il(32)][e(8)]  (2048 elems)
//     element (row il, c = kc*16+hi*8+e)
//   V  per (b, 32-col tile):  [G(2)][vh(2)][il(32)][ct(2)][e(8)] (2048 elems)
//     element (c = ct*32+il, j = G*16+vh*8+e)  -- A-frag-major for 32x32x16
// attn (round 13): 256 blocks x 8 waves; block = (b, 64-row Q-tile);
//   wave w owns j-tiles [w*16, w*16+16).  PV full-rate 32x32x16 via bf16x2
//   packs + v_permlane32_swap_b32.  Latency package: V double-buffered like K
//   (12 loads in flight, V consume-distance = full iteration), st zero-init
//   from persistent zf C-operand (-32 v_mov/t), exp2 feeds packs directly.
// ---------------------------------------------------------------------------

typedef __bf16 bf16x2 __attribute__((ext_vector_type(2)));
typedef __bf16 bf16x4 __attribute__((ext_vector_type(4)));
typedef __bf16 bf16x8 __attribute__((ext_vector_type(8)));
typedef float  f32x4  __attribute__((ext_vector_type(4)));
typedef float  f32x16 __attribute__((ext_vector_type(16)));

constexpr int C = 64;
constexpr int N = 4096;
constexpr float LOG2E = 1.44269504088896340736f;

static __device__ __forceinline__ f32x4 mfma16(bf16x8 a, bf16x8 b, f32x4 c) {
    return __builtin_amdgcn_mfma_f32_16x16x32_bf16(a, b, c, 0, 0, 0);
}
static __device__ __forceinline__ f32x16 mfma32(bf16x8 a, bf16x8 b, f32x16 c) {
    return __builtin_amdgcn_mfma_f32_32x32x16_bf16(a, b, c, 0, 0, 0);
}
static __device__ __forceinline__ float fast_exp2(float x) {
#if __has_builtin(__builtin_amdgcn_exp2f)
    return __builtin_amdgcn_exp2f(x);
#else
    return exp2f(x);
#endif
}
static __device__ __forceinline__ uint32_t pack2(float a, float b) {
    union { uint32_t u; bf16x2 h; } w;
    w.h = bf16x2{(__bf16)a, (__bf16)b};
    return w.u;
}

// ---------------------------------------------------------------------------
// QKV conv, 3-way split. grid = 768 x 256 thr. kind = bid>>8: 0=Q, 1=K, 2=V.
// Each block: one projection, 64 pixels, 4 waves x 16 pixels.
//   Q,K: D[n][o] = X^T W^T (A = x frag, B = W row-major from LDS)
//   V  : D[o][n] = W X     (A = W row-major from LDS, B = x frag)
// Results round-trip a padded LDS transpose so all global stores are 16B.
// ---------------------------------------------------------------------------
__global__ __launch_bounds__(256) void qkv_kernel(
    const float* __restrict__ x1, const float* __restrict__ x2,
    const float* __restrict__ wq, const float* __restrict__ bq,
    const float* __restrict__ wk, const float* __restrict__ bk,
    const float* __restrict__ wv, const float* __restrict__ bv,
    __bf16* __restrict__ qo, __bf16* __restrict__ ko, __bf16* __restrict__ vo)
{
    __shared__ __bf16 wl[64][72];     // W row-major, 9 KB
    __shared__ __bf16 tout[64][72];   // [pixel][o] transpose buffer, 9 KB

    const int bid  = blockIdx.x;
    const int kind = bid >> 8;                 // 0=Q, 1=K, 2=V (block-uniform)
    const int pg   = bid & 255;
    const int b     = pg >> 6;
    const int nbase = (pg & 63) * 64;
    const int tid   = threadIdx.x;

    const float* wsel = kind == 0 ? wq : (kind == 1 ? wk : wv);
    const float* bsel = kind == 0 ? bq : (kind == 1 ? bk : bv);
    const float* xsel = kind == 0 ? x1 : x2;
    __bf16*      osel = kind == 0 ? qo : (kind == 1 ? ko : vo);

    // ---- stage W (64x64 fp32 -> bf16 LDS) ----
#pragma unroll
    for (int i = 0; i < 4; ++i) {
        int idx = i * 256 + tid;
        int row = idx >> 4, c4 = (idx & 15) * 4;
        float4 a = *(const float4*)(wsel + row * 64 + c4);
        bf16x4 h = {(__bf16)a.x, (__bf16)a.y, (__bf16)a.z, (__bf16)a.w};
        *(bf16x4*)&wl[row][c4] = h;
    }
    __syncthreads();

    const int wave = tid >> 6, lane = tid & 63;
    const int l = lane & 15, qd = lane >> 4;
    const int p = nbase + wave * 16 + l;       // this lane's pixel

    // x fragment: A/B[k=c][pixel p], c = ks*32 + qd*8 + j
    const float* xb = xsel + (size_t)b * C * N + p;
    bf16x8 ax[2];
#pragma unroll
    for (int ks = 0; ks < 2; ++ks)
#pragma unroll
        for (int j = 0; j < 8; ++j)
            ax[ks][j] = (__bf16)xb[(size_t)(ks * 32 + qd * 8 + j) * N];

    if (kind < 2) {
        // ---- Q/K: D[pixel][o] ----
        const float scale = kind == 0 ? LOG2E : 1.0f;
#pragma unroll
        for (int ot = 0; ot < 4; ++ot) {
            const float bb = bsel[ot * 16 + l];
            f32x4 acc = {bb, bb, bb, bb};
#pragma unroll
            for (int ks = 0; ks < 2; ++ks) {
                bf16x8 bw = *(const bf16x8*)&wl[ot * 16 + l][ks * 32 + qd * 8];
                acc = mfma16(ax[ks], bw, acc);
            }
#pragma unroll
            for (int r = 0; r < 4; ++r) {
                int px = wave * 16 + qd * 4 + r;
                tout[px][ot * 16 + l] = (__bf16)(acc[r] * scale);
            }
        }
        __syncthreads();

        // ---- drain: frag-major 16B contiguous stores ----
        const int tile = tid >> 7, t7 = tid & 127;
        const int kc = t7 >> 5, h2 = (t7 >> 4) & 1, ilp = (t7 & 15) * 2;
        const size_t tb = ((size_t)b * 128 + (nbase >> 5) + tile) * 2048;
        const size_t off = tb + kc * 512 + h2 * 256 + ilp * 8;
        bf16x8 ra = *(const bf16x8*)&tout[tile * 32 + ilp][kc * 16 + h2 * 8];
        bf16x8 rb = *(const bf16x8*)&tout[tile * 32 + ilp + 1][kc * 16 + h2 * 8];
        *(bf16x8*)&osel[off]     = ra;
        *(bf16x8*)&osel[off + 8] = rb;
    } else {
        // ---- V: D[o][pixel] -> tout[pixel][o] ----
#pragma unroll
        for (int ct = 0; ct < 4; ++ct) {
            f32x4 acc;
#pragma unroll
            for (int r = 0; r < 4; ++r) acc[r] = bsel[ct * 16 + qd * 4 + r];
#pragma unroll
            for (int ks = 0; ks < 2; ++ks) {
                bf16x8 aw = *(const bf16x8*)&wl[ct * 16 + l][ks * 32 + qd * 8];
                acc = mfma16(aw, ax[ks], acc);
            }
            bf16x4 pk = {(__bf16)acc[0], (__bf16)acc[1], (__bf16)acc[2], (__bf16)acc[3]};
            *(bf16x4*)&tout[wave * 16 + l][ct * 16 + qd * 4] = pk;
        }
        __syncthreads();

        // ---- drain: [G][vh][il][ct][e8], two 16B stores per thread ----
        // element (c = ct*32+il, j = G*16+vh*8+e) at G*1024+vh*512+il*16+ct*8+e
        const int tile = tid >> 7, t7 = tid & 127;
        const int G = t7 >> 6, vh = (t7 >> 5) & 1, il = t7 & 31;
        const int pxb = tile * 32 + G * 16 + vh * 8;   // pixel row of e=0
        bf16x8 oA, oB;
#pragma unroll
        for (int e = 0; e < 8; ++e) {
            oA[e] = tout[pxb + e][il];        // ct = 0
            oB[e] = tout[pxb + e][32 + il];   // ct = 1
        }
        const size_t tb = ((size_t)b * 128 + (nbase >> 5) + tile) * 2048;
        const size_t off = tb + G * 1024 + vh * 512 + (size_t)il * 16;
        *(bf16x8*)&osel[off]     = oA;
        *(bf16x8*)&osel[off + 8] = oB;
    }
}

// ---------------------------------------------------------------------------
// Attention. grid = 256 blocks x 512 thr (8 waves).
// Block = (b, 64-row Q-tile = 2 subtiles); wave w owns j-tiles [w*16,w*16+16).
// 32x32x16: A/B 8 elems k=(lane>>5)*8+j; C/D row=(r&3)+8*(r>>2)+4*hi, col=il.
// PV full-rate: P^T B-frags built by pairing exp2 outputs into bf16x2 words
// and exchanging halves with v_permlane32_swap_b32.
// ---------------------------------------------------------------------------
__global__ __launch_bounds__(512, 2) void attn_kernel(
    const __bf16* __restrict__ qg, const __bf16* __restrict__ kg,
    const __bf16* __restrict__ vg, const float* __restrict__ x1,
    const float* __restrict__ gamma, float* __restrict__ out)
{
    __shared__ float lds_acc[3][64][64];   // 3 combine slots, 48 KB, [c][i]
    __shared__ float lds_l[8][64];         // per-wave lsum partials, [w][i]

    const int bid = blockIdx.x;                      // 0..255
    const int xcd = bid & 7;
    const int b   = xcd >> 1;
    const int rt  = ((bid >> 3) << 1) | (xcd & 1);   // 0..63 (64-row tile)
    const int ibase = rt * 64;

    const int tid  = threadIdx.x;
    const int wave = tid >> 6, lane = tid & 63;
    const int il = lane & 31, hi = lane >> 5;

    const __bf16* qt = qg + ((size_t)b * 128 + rt * 2) * 2048;
    const __bf16* kt = kg + (size_t)b * 128 * 2048 + (size_t)(wave * 16) * 2048;
    const __bf16* vt = vg + (size_t)b * 128 * 2048 + (size_t)(wave * 16) * 2048;

    // Q B-frags for both 32-row subtiles: 1 KB contiguous per load
    bf16x8 bqf[2][4];
#pragma unroll
    for (int qs = 0; qs < 2; ++qs)
#pragma unroll
        for (int kc = 0; kc < 4; ++kc)
            bqf[qs][kc] = *(const bf16x8*)(qt + qs * 2048 + kc * 512 + lane * 8);

    // persistent zero C-operand (replaces per-t st zero-init v_movs)
    f32x16 zf;
#pragma unroll
    for (int r = 0; r < 16; ++r) zf[r] = 0.f;

    f32x16 accO[4];   // [qs*2 + ct]
#pragma unroll
    for (int a = 0; a < 4; ++a)
#pragma unroll
        for (int r = 0; r < 16; ++r) accO[a][r] = 0.f;
    float lsum[2] = {0.f, 0.f};

    bf16x8 akf[2][4];      // K frags, double-buffered
    bf16x8 avf[2][2][2];   // V frags, double-buffered [buf][ct][G]

#pragma unroll
    for (int kc = 0; kc < 4; ++kc)
        akf[0][kc] = *(const bf16x8*)(kt + kc * 512 + lane * 8);
#pragma unroll
    for (int ct = 0; ct < 2; ++ct)
#pragma unroll
        for (int G = 0; G < 2; ++G)
            avf[0][ct][G] = *(const bf16x8*)(vt + G * 1024 + hi * 512 + il * 16 + ct * 8);

#pragma unroll 2
    for (int t = 0; t < 16; ++t) {
        const int cur = t & 1;
        if (t < 15) {
            const size_t nb = (size_t)(t + 1) * 2048;
#pragma unroll
            for (int kc = 0; kc < 4; ++kc)
                akf[cur ^ 1][kc] = *(const bf16x8*)(kt + nb + kc * 512 + lane * 8);
#pragma unroll
            for (int ct = 0; ct < 2; ++ct)
#pragma unroll
                for (int G = 0; G < 2; ++G)
                    avf[cur ^ 1][ct][G] = *(const bf16x8*)(vt + nb + G * 1024 + hi * 512 + il * 16 + ct * 8);
        }

#pragma unroll
        for (int qs = 0; qs < 2; ++qs) {
            // S^T = K Q^T for this Q-subtile (zf C-operand, no v_mov init)
            f32x16 st = mfma32(akf[cur][0], bqf[qs][0], zf);
#pragma unroll
            for (int kc = 1; kc < 4; ++kc) st = mfma32(akf[cur][kc], bqf[qs][kc], st);

            // p = exp2(S') (no shift; constant cancels in O/l) -> packs
            float e0, e1;
            float lp0 = 0.f, lp1 = 0.f;
            uint32_t a0, a1, b0, b1, c0, c1, d0, d1;
            e0 = fast_exp2(st[0]);  e1 = fast_exp2(st[1]);
            lp0 += e0; lp1 += e1; a0 = pack2(e0, e1);
            e0 = fast_exp2(st[2]);  e1 = fast_exp2(st[3]);
            lp0 += e0; lp1 += e1; a1 = pack2(e0, e1);
            e0 = fast_exp2(st[4]);  e1 = fast_exp2(st[5]);
            lp0 += e0; lp1 += e1; b0 = pack2(e0, e1);
            e0 = fast_exp2(st[6]);  e1 = fast_exp2(st[7]);
            lp0 += e0; lp1 += e1; b1 = pack2(e0, e1);
            e0 = fast_exp2(st[8]);  e1 = fast_exp2(st[9]);
            lp0 += e0; lp1 += e1; c0 = pack2(e0, e1);
            e0 = fast_exp2(st[10]); e1 = fast_exp2(st[11]);
            lp0 += e0; lp1 += e1; c1 = pack2(e0, e1);
            e0 = fast_exp2(st[12]); e1 = fast_exp2(st[13]);
            lp0 += e0; lp1 += e1; d0 = pack2(e0, e1);
            e0 = fast_exp2(st[14]); e1 = fast_exp2(st[15]);
            lp0 += e0; lp1 += e1; d1 = pack2(e0, e1);
            lsum[qs] += lp0 + lp1;

            // exchange halves: frag G needs j = G*16 + hi*8 + {0..7}
            asm("v_permlane32_swap_b32 %0, %1" : "+v"(a0), "+v"(b0));
            asm("v_permlane32_swap_b32 %0, %1" : "+v"(a1), "+v"(b1));
            asm("v_permlane32_swap_b32 %0, %1" : "+v"(c0), "+v"(d0));
            asm("v_permlane32_swap_b32 %0, %1" : "+v"(c1), "+v"(d1));
            union F { uint32_t u[4]; bf16x8 v; } f0, f1;
            f0.u[0] = a0; f0.u[1] = a1; f0.u[2] = b0; f0.u[3] = b1;
            f1.u[0] = c0; f1.u[1] = c1; f1.u[2] = d0; f1.u[3] = d1;

            // O^T += V P^T (full-rate 32x32x16)
#pragma unroll
            for (int ct = 0; ct < 2; ++ct) {
                accO[qs * 2 + ct] = mfma32(avf[cur][ct][0], f0.v, accO[qs * 2 + ct]);
                accO[qs * 2 + ct] = mfma32(avf[cur][ct][1], f1.v, accO[qs * 2 + ct]);
            }
        }
    }

    // per-lane lsum -> per-column(i) sum within wave (pair hi halves)
#pragma unroll
    for (int qs = 0; qs < 2; ++qs) lsum[qs] += __shfl_xor(lsum[qs], 32);
    if (hi == 0) {
        lds_l[wave][il]      = lsum[0];
        lds_l[wave][32 + il] = lsum[1];
    }

    // ---- cross-wave combine: 3-slot LDS tree ----
    // accO element (qs,ct,r) -> c = ct*32+(r&3)+8*(r>>2)+4*hi, i = qs*32+il
#define ACC_STORE(SLOT)                                                        \
    do {                                                                       \
        _Pragma("unroll")                                                      \
        for (int qs = 0; qs < 2; ++qs)                                         \
            _Pragma("unroll")                                                  \
            for (int ct = 0; ct < 2; ++ct)                                     \
                _Pragma("unroll")                                              \
                for (int r = 0; r < 16; ++r)                                   \
                    lds_acc[SLOT][ct * 32 + (r & 3) + 8 * (r >> 2) + 4 * hi][qs * 32 + il] = accO[qs * 2 + ct][r]; \
    } while (0)
#define ACC_LOAD(SLOT)                                                         \
    do {                                                                       \
        _Pragma("unroll")                                                      \
        for (int qs = 0; qs < 2; ++qs)                                         \
            _Pragma("unroll")                                                  \
            for (int ct = 0; ct < 2; ++ct)                                     \
                _Pragma("unroll")                                              \
                for (int r = 0; r < 16; ++r)                                   \
                    accO[qs * 2 + ct][r] += lds_acc[SLOT][ct * 32 + (r & 3) + 8 * (r >> 2) + 4 * hi][qs * 32 + il]; \
    } while (0)

    if (wave >= 5) ACC_STORE(wave - 5);                 // w5->0, w6->1, w7->2
    __syncthreads();
    if (wave >= 1 && wave <= 3) ACC_LOAD(wave - 1);     // w1+=w5, w2+=w6, w3+=w7
    __syncthreads();
    if (wave >= 2 && wave <= 4) ACC_STORE(wave - 2);    // w2->0, w3->1, w4->2
    __syncthreads();
    if (wave <= 1) ACC_LOAD(wave);                      // w0+=(w2+w6), w1+=(w3+w7)
    if (wave == 0) ACC_LOAD(2);                         // w0+=w4
    __syncthreads();
    if (wave == 1) ACC_STORE(0);                        // (w1+w5+w3+w7) -> s0
    __syncthreads();
    if (wave == 0) { ACC_LOAD(0); ACC_STORE(0); }       // total -> s0
    __syncthreads();
#undef ACC_STORE
#undef ACC_LOAD

    // ---- epilogue: out = gamma*O/l + x1 ----
    const float g = gamma[0];
    {
        const int c  = tid >> 3;           // 0..63
        const int i8 = (tid & 7) * 8;      // 0..56
        float lv[8];
#pragma unroll
        for (int e = 0; e < 8; ++e) {
            float s = 0.f;
#pragma unroll
            for (int w = 0; w < 8; ++w) s += lds_l[w][i8 + e];
            lv[e] = s;
        }
        const size_t idx = ((size_t)b * C + c) * N + ibase + i8;
        f32x4 o0 = *(const f32x4*)&lds_acc[0][c][i8];
        f32x4 o1 = *(const f32x4*)&lds_acc[0][c][i8 + 4];
        f32x4 x0 = *(const f32x4*)(x1 + idx);
        f32x4 x4 = *(const f32x4*)(x1 + idx + 4);
        f32x4 r0, r1;
#pragma unroll
        for (int e = 0; e < 4; ++e) {
            r0[e] = g * o0[e] / lv[e] + x0[e];
            r1[e] = g * o1[e] / lv[4 + e] + x4[e];
        }
        *(f32x4*)(out + idx) = r0;
        *(f32x4*)(out + idx + 4) = r1;
    }
}

// ---------------------------------------------------------------------------
extern "C" void kernel_launch(void* const* d_in, const int* in_sizes, int n_in,
                              void* d_out, int out_size, void* d_ws, size_t ws_size,
                              hipStream_t stream) {
    const float* x1    = (const float*)d_in[0];
    const float* x2    = (const float*)d_in[1];
    const float* wq    = (const float*)d_in[2];
    const float* bqv   = (const float*)d_in[3];
    const float* wk    = (const float*)d_in[4];
    const float* bkv   = (const float*)d_in[5];
    const float* wv    = (const float*)d_in[6];
    const float* bvv   = (const float*)d_in[7];
    const float* gamma = (const float*)d_in[8];
    float* out = (float*)d_out;

    __bf16* qws = (__bf16*)d_ws;                   // tiled Q, 2 MB
    __bf16* kws = qws + (size_t)4 * 128 * 2048;    // tiled K, 2 MB
    __bf16* vws = kws + (size_t)4 * 128 * 2048;    // tiled V, 2 MB

    qkv_kernel<<<768, 256, 0, stream>>>(x1, x2, wq, bqv, wk, bkv, wv, bvv, qws, kws, vws);
    attn_kernel<<<256, 512, 0, stream>>>(qws, kws, vws, x1, gamma, out);
}